// Round 3
// baseline (314.981 us; speedup 1.0000x reference)
//
#include <hip/hip_runtime.h>
#include <hip/hip_bf16.h>

#define BB 16
#define CIN 256
#define COUT 256
#define HH 64
#define WW 64
#define SDIM 512
#define XP 66          // padded spatial dim
#define XPP (XP * XP)

typedef __attribute__((ext_vector_type(8))) short bf16x8;
typedef __attribute__((ext_vector_type(4))) float f32x4;

static __device__ __forceinline__ short f2bf(float v) {
    __hip_bfloat16 h = __float2bfloat16(v);
    return *reinterpret_cast<short*>(&h);
}

// ---- kernel 1: wT[co][k][ci] bf16  +  wsqT[ci][co] = sum_k w^2 (fp32) ----
__global__ void wfuse_kernel(const float* __restrict__ w,
                             __hip_bfloat16* __restrict__ wT,
                             float* __restrict__ wsqT) {
    int co = blockIdx.x;   // 256
    int ci = threadIdx.x;  // 256
    const float* wp = w + ((size_t)co * CIN + ci) * 9;
    float q = 0.f;
#pragma unroll
    for (int k = 0; k < 9; ++k) {
        float v = wp[k];
        q += v * v;
        wT[((size_t)co * 9 + k) * CIN + ci] = __float2bfloat16(v);
    }
    wsqT[(size_t)ci * COUT + co] = q;
}

// ---- kernel 2: s[b][ci] (fp32) + demod[b][co] (fp32), one block per b ----
__global__ __launch_bounds__(256) void sdemod_kernel(
    const float* __restrict__ style, const float* __restrict__ style_w,
    const float* __restrict__ style_b, const float* __restrict__ wsqT,
    float* __restrict__ s, float* __restrict__ demod) {
    int b = blockIdx.x, t = threadIdx.x;
    __shared__ float sl[CIN];
    float acc = style_b[t];
    const float* st = style + b * SDIM;
#pragma unroll 4
    for (int sd = 0; sd < SDIM; ++sd)
        acc += st[sd] * style_w[sd * CIN + t];
    sl[t] = acc;
    s[b * CIN + t] = acc;
    __syncthreads();
    float d = 0.f;
#pragma unroll 4
    for (int ci = 0; ci < CIN; ++ci) {
        float sv = sl[ci];  // LDS broadcast
        d += wsqT[(size_t)ci * COUT + t] * sv * sv;  // coalesced across t
    }
    demod[b * COUT + t] = rsqrtf(d * (1.0f / (CIN * 9)) + 1e-8f);
}

// ---- kernel 3: xpad[b][cc][py][quad][px][ci8] = bf16(x*s), zero halo ----
__global__ __launch_bounds__(256) void xmod_kernel(
    const float* __restrict__ x, const float* __restrict__ s,
    __hip_bfloat16* __restrict__ xpad) {
    int py = blockIdx.x;  // 0..65 padded row
    int cc = blockIdx.y;  // 0..7
    int b  = blockIdx.z;
    int tid = threadIdx.x;
    __hip_bfloat16* outp = xpad + ((size_t)(b * 8 + cc) * XPP + (size_t)py * XP) * 32;
    if (py == 0 || py == XP - 1) {
        for (int f = tid; f < 264; f += 256)
            *(bf16x8*)(outp + f * 8) = (bf16x8){0, 0, 0, 0, 0, 0, 0, 0};
        return;
    }
    __shared__ float lds[32 * 65];  // [ci32][px64], stride 65
    const float4* xrow =
        (const float4*)(x + ((size_t)(b * CIN + cc * 32) * HH + (py - 1)) * WW);
#pragma unroll
    for (int i = 0; i < 2; ++i) {
        int f = i * 256 + tid;          // 512 float4 slots = 32 ci x 16
        int cil = f >> 4, c4 = f & 15;
        float4 v = xrow[(size_t)cil * (HH * WW / 4) + c4];
        float sv = s[b * CIN + cc * 32 + cil];
        lds[cil * 65 + c4 * 4 + 0] = v.x * sv;
        lds[cil * 65 + c4 * 4 + 1] = v.y * sv;
        lds[cil * 65 + c4 * 4 + 2] = v.z * sv;
        lds[cil * 65 + c4 * 4 + 3] = v.w * sv;
    }
    __syncthreads();
    for (int f = tid; f < 264; f += 256) {  // 4 quads x 66 px
        int q = f / 66, px = f - q * 66;
        bf16x8 v = (bf16x8){0, 0, 0, 0, 0, 0, 0, 0};
        if (px > 0 && px < 65) {
#pragma unroll
            for (int c = 0; c < 8; ++c)
                v[c] = f2bf(lds[(q * 8 + c) * 65 + px - 1]);
        }
        *(bf16x8*)(outp + f * 8) = v;  // 16B/lane, contiguous across f
    }
}

// ---- kernel 4: implicit-GEMM conv via bf16 MFMA --------------------------
// block: 4 waves = 2 co-halves x 2 rows -> 64 co x (2 rows x 64 px)
// LDS x-tile layout: [row4][quad4][col66][ci8]  (conflict-free b128 reads)
__global__ __launch_bounds__(256, 3) void conv_mfma_kernel(
    const __hip_bfloat16* __restrict__ xpad,
    const __hip_bfloat16* __restrict__ wT,
    const float* __restrict__ demod,
    float* __restrict__ out) {
    __shared__ __hip_bfloat16 xs[4 * 4 * XP * 8];  // 16896 B

    int tid  = threadIdx.x;
    int lane = tid & 63;
    int wave = tid >> 6;
    int wco  = wave >> 1;  // co half
    int wr   = wave & 1;   // output row within tile
    int n    = lane & 15;
    int quad = lane >> 4;

    int sp  = blockIdx.x;       // 0..31 (2 output rows each)
    int co0 = blockIdx.y * 64;  // 0..3
    int b   = blockIdx.z;
    int y0  = sp * 2;           // padded rows y0..y0+3

    f32x4 acc[2][4];
#pragma unroll
    for (int i = 0; i < 2; ++i)
#pragma unroll
        for (int j = 0; j < 4; ++j) acc[i][j] = (f32x4){0.f, 0.f, 0.f, 0.f};

    const __hip_bfloat16* wb =
        wT + (size_t)(co0 + wco * 32) * 9 * CIN + quad * 8;

    for (int cc = 0; cc < 8; ++cc) {
        __syncthreads();  // prior readers done before LDS overwrite
        // stage 4 rows x (4 quads x 66 cols x 8 ci) = 16896 B, contiguous
        const __hip_bfloat16* src =
            xpad + ((size_t)(b * 8 + cc) * XPP + (size_t)y0 * XP) * 32;
#pragma unroll
        for (int t = 0; t < 4; ++t) {
            __builtin_amdgcn_global_load_lds(
                (const __attribute__((address_space(1))) void*)(src + ((size_t)t * 256 + tid) * 8),
                (__attribute__((address_space(3))) void*)(xs + (t * 256 + (tid & ~63)) * 8),
                16, 0, 0);
        }
        if (tid < 32) {
            __builtin_amdgcn_global_load_lds(
                (const __attribute__((address_space(1))) void*)(src + (size_t)(1024 + tid) * 8),
                (__attribute__((address_space(3))) void*)(xs + 1024 * 8),
                16, 0, 0);
        }
        // A-frag prefetch for this cc: issued before the barrier so L2
        // latency overlaps the staging drain (one exposure per cc, not 9)
        bf16x8 af[2][9];
        const __hip_bfloat16* wbc = wb + cc * 32;
#pragma unroll
        for (int k = 0; k < 9; ++k) {
            af[0][k] = *(const bf16x8*)(wbc + (size_t)(n * 9 + k) * CIN);
            af[1][k] = *(const bf16x8*)(wbc + (size_t)((16 + n) * 9 + k) * CIN);
        }
        __syncthreads();  // drains vmcnt(0): staging + A loads complete

#pragma unroll
        for (int k = 0; k < 9; ++k) {
            int dy = k / 3, dx = k - dy * 3;
            const __hip_bfloat16* bp =
                &xs[((((wr + dy) * 4 + quad) * XP) + n + dx) * 8];
#pragma unroll
            for (int j = 0; j < 4; ++j) {
                bf16x8 bv = *(const bf16x8*)(bp + j * 16 * 8);
                acc[0][j] = __builtin_amdgcn_mfma_f32_16x16x32_bf16(af[0][k], bv, acc[0][j], 0, 0, 0);
                acc[1][j] = __builtin_amdgcn_mfma_f32_16x16x32_bf16(af[1][k], bv, acc[1][j], 0, 0, 0);
            }
        }
    }

    // epilogue: C/D layout col=lane&15 (px), row=quad*4+reg (co)
    int gy = y0 + wr;
    const float ms = 1.0f / 48.0f;
#pragma unroll
    for (int i = 0; i < 2; ++i) {
        int cobase = co0 + wco * 32 + i * 16 + quad * 4;
        float d0 = demod[b * COUT + cobase + 0] * ms;
        float d1 = demod[b * COUT + cobase + 1] * ms;
        float d2 = demod[b * COUT + cobase + 2] * ms;
        float d3 = demod[b * COUT + cobase + 3] * ms;
#pragma unroll
        for (int j = 0; j < 4; ++j) {
            int gx = j * 16 + n;
            size_t o = ((size_t)(b * COUT + cobase) * HH + gy) * WW + gx;
            out[o]                   = acc[i][j][0] * d0;
            out[o + (size_t)HH * WW]     = acc[i][j][1] * d1;
            out[o + (size_t)2 * HH * WW] = acc[i][j][2] * d2;
            out[o + (size_t)3 * HH * WW] = acc[i][j][3] * d3;
        }
    }
}

extern "C" void kernel_launch(void* const* d_in, const int* in_sizes, int n_in,
                              void* d_out, int out_size, void* d_ws, size_t ws_size,
                              hipStream_t stream) {
    const float* x       = (const float*)d_in[0];  // [16,256,64,64]
    const float* style   = (const float*)d_in[1];  // [16,512]
    const float* weight  = (const float*)d_in[2];  // [256,256,3,3]
    const float* style_w = (const float*)d_in[3];  // [512,256]
    const float* style_b = (const float*)d_in[4];  // [256]
    float* out = (float*)d_out;

    // ws: s[4096]f | wsqT[65536]f | demod[4096]f | wT[589824]bf16 | xpad bf16
    float* s     = (float*)d_ws;
    float* wsqT  = s + BB * CIN;
    float* demod = wsqT + COUT * CIN;
    __hip_bfloat16* wT   = (__hip_bfloat16*)(demod + BB * COUT);
    __hip_bfloat16* xpad = wT + (size_t)COUT * 9 * CIN;

    wfuse_kernel<<<COUT, CIN, 0, stream>>>(weight, wT, wsqT);
    sdemod_kernel<<<BB, 256, 0, stream>>>(style, style_w, style_b, wsqT, s, demod);
    xmod_kernel<<<dim3(XP, 8, BB), 256, 0, stream>>>(x, s, xpad);
    conv_mfma_kernel<<<dim3(32, COUT / 64, BB), 256, 0, stream>>>(xpad, wT, demod, out);
}

// Round 4
// 277.048 us; speedup vs baseline: 1.1369x; 1.1369x over previous
//
#include <hip/hip_runtime.h>
#include <hip/hip_bf16.h>

#define BB 16
#define CIN 256
#define COUT 256
#define HH 64
#define WW 64
#define SDIM 512

typedef __attribute__((ext_vector_type(8))) short bf16x8;
typedef __attribute__((ext_vector_type(4))) float f32x4;

static __device__ __forceinline__ short f2bf(float v) {
    __hip_bfloat16 h = __float2bfloat16(v);
    return *reinterpret_cast<short*>(&h);
}

// ---------------- kernel 1: style projection s[b,ci] (R1, proven cheap) ----
__global__ void style_proj_kernel(const float* __restrict__ style,
                                  const float* __restrict__ style_w,
                                  const float* __restrict__ style_b,
                                  float* __restrict__ s) {
    int ci = threadIdx.x;
    int b  = blockIdx.x;
    float acc = style_b[ci];
    const float* st = style + b * SDIM;
    for (int sd = 0; sd < SDIM; ++sd)
        acc += st[sd] * style_w[sd * CIN + ci];
    s[b * CIN + ci] = acc;
}

// ---------------- kernel 2: wsq[co,ci] = sum_k w^2 (R1) ----------------
__global__ void wsq_kernel(const float* __restrict__ weight,
                           float* __restrict__ wsq) {
    int idx = blockIdx.x * blockDim.x + threadIdx.x;  // co*CIN+ci
    const float* w = weight + (size_t)idx * 9;
    float acc = 0.f;
#pragma unroll
    for (int k = 0; k < 9; ++k) acc += w[k] * w[k];
    wsq[idx] = acc;
}

// ---------------- kernel 3: demod[b,co] (R2, 1024 blocks) ----------------
__global__ void demod_kernel(const float* __restrict__ wsq,
                             const float* __restrict__ s,
                             float* __restrict__ demod) {
    int b    = blockIdx.y;
    int co   = blockIdx.x * 4 + (threadIdx.x >> 6);
    int lane = threadIdx.x & 63;
    float acc = 0.f;
#pragma unroll
    for (int j = 0; j < CIN / 64; ++j) {
        int ci = j * 64 + lane;
        float sv = s[b * CIN + ci];
        acc += wsq[co * CIN + ci] * sv * sv;
    }
#pragma unroll
    for (int off = 32; off > 0; off >>= 1)
        acc += __shfl_down(acc, off, 64);
    if (lane == 0)
        demod[b * COUT + co] = rsqrtf(acc * (1.0f / (CIN * 9)) + 1e-8f);
}

// ---------------- kernel 4: weight transform -> bf16 wT[co][k][ci] -------
__global__ void wconv_kernel(const float* __restrict__ w,
                             __hip_bfloat16* __restrict__ wT) {
    int co = blockIdx.x;   // 256
    int ci = threadIdx.x;  // 256
#pragma unroll
    for (int k = 0; k < 9; ++k)
        wT[((size_t)co * 9 + k) * CIN + ci] =
            __float2bfloat16(w[((size_t)co * CIN + ci) * 9 + k]);
}

// ---- stage one ci-chunk (cc) into LDS buffer: [row6][quad4][col66][ci8] ---
// lane -> pixel: 8 coalesced 256B loads per unit, pack bf16x8, 1 ds_write_b128
__device__ __forceinline__ void stage_tile(
    __hip_bfloat16* __restrict__ xsb,
    const float* __restrict__ x, const float* __restrict__ s,
    int b, int cc, int Y0, int lane, int wave) {
#pragma unroll
    for (int i = 0; i < 6; ++i) {
        int u = wave * 6 + i;          // 24 (row,quad) units, 6 per wave
        int r = u >> 2, quad = u & 3;
        int y = Y0 - 1 + r;
        bf16x8 wv = (bf16x8){0, 0, 0, 0, 0, 0, 0, 0};
        if ((unsigned)y < (unsigned)HH) {
            const float* base =
                x + (((size_t)(b * CIN + cc * 32 + quad * 8)) * HH + y) * WW + lane;
            const float4* sp = (const float4*)(s + b * CIN + cc * 32 + quad * 8);
            float4 s0 = sp[0], s1 = sp[1];
            float sv[8] = {s0.x, s0.y, s0.z, s0.w, s1.x, s1.y, s1.z, s1.w};
#pragma unroll
            for (int c = 0; c < 8; ++c)
                wv[c] = f2bf(base[(size_t)c * (HH * WW)] * sv[c]);
        }
        *(bf16x8*)(xsb + (((r * 4 + quad) * 66) + 1 + lane) * 8) = wv;
        if (lane < 2) {  // zero halo cols 0 and 65
            bf16x8 z = (bf16x8){0, 0, 0, 0, 0, 0, 0, 0};
            *(bf16x8*)(xsb + (((r * 4 + quad) * 66) + lane * 65) * 8) = z;
        }
    }
}

// ---- kernel 5: fused modulated conv, bf16 MFMA, double-buffered ----------
// block: 4 waves = 2 co-halves x 2 row-pairs -> 64 co x 4 rows x 64 px
// wave tile: 32 co x 2 rows x 64 px; B-reads shared across the row pair
__global__ __launch_bounds__(256, 2) void conv_mfma_kernel(
    const float* __restrict__ x, const __hip_bfloat16* __restrict__ wT,
    const float* __restrict__ s, const float* __restrict__ demod,
    float* __restrict__ out) {
    __shared__ __hip_bfloat16 xs[2][6 * 4 * 66 * 8];  // 2 x 25344 B

    int tid  = threadIdx.x;
    int lane = tid & 63;
    int wave = tid >> 6;
    int wco  = wave >> 1;  // co half
    int rp   = wave & 1;   // row pair (rows rp*2, rp*2+1)
    int n    = lane & 15;
    int quad = lane >> 4;

    int Y0  = blockIdx.x * 4;   // 16 spatial blocks x 4 output rows
    int co0 = blockIdx.y * 64;  // 4 co blocks
    int b   = blockIdx.z;

    f32x4 acc[2][2][4];  // [wr][m][j]
#pragma unroll
    for (int wr = 0; wr < 2; ++wr)
#pragma unroll
        for (int m = 0; m < 2; ++m)
#pragma unroll
            for (int j = 0; j < 4; ++j) acc[wr][m][j] = (f32x4){0.f, 0.f, 0.f, 0.f};

    // A base: wT[co][k][ci]; this wave's A rows: co0 + wco*32 + m*16 + n
    const __hip_bfloat16* wb =
        wT + ((size_t)(co0 + wco * 32 + n) * 9) * CIN + quad * 8;

    stage_tile(xs[0], x, s, b, 0, Y0, lane, wave);
    __syncthreads();

    for (int cc = 0; cc < 8; ++cc) {
        int cur = cc & 1;
        // stage next chunk into the other buffer; overlaps MFMA below
        if (cc < 7) stage_tile(xs[cur ^ 1], x, s, b, cc + 1, Y0, lane, wave);

        bf16x8 af[2][9];
#pragma unroll
        for (int k = 0; k < 9; ++k) {
            af[0][k] = *(const bf16x8*)(wb + ((size_t)k) * CIN + cc * 32);
            af[1][k] = *(const bf16x8*)(wb + ((size_t)(16 * 9 + k)) * CIN + cc * 32);
        }

        const __hip_bfloat16* xb = xs[cur];
#pragma unroll
        for (int r4 = 0; r4 < 4; ++r4) {
            int rr = rp * 2 + r4;  // LDS row; x row = Y0 - 1 + rr
#pragma unroll
            for (int dx = 0; dx < 3; ++dx) {
#pragma unroll
                for (int j = 0; j < 4; ++j) {
                    bf16x8 bv = *(const bf16x8*)(
                        xb + (((rr * 4 + quad) * 66) + j * 16 + n + dx) * 8);
                    if (r4 <= 2) {  // wr=0, dy=r4
                        acc[0][0][j] = __builtin_amdgcn_mfma_f32_16x16x32_bf16(
                            af[0][r4 * 3 + dx], bv, acc[0][0][j], 0, 0, 0);
                        acc[0][1][j] = __builtin_amdgcn_mfma_f32_16x16x32_bf16(
                            af[1][r4 * 3 + dx], bv, acc[0][1][j], 0, 0, 0);
                    }
                    if (r4 >= 1) {  // wr=1, dy=r4-1
                        acc[1][0][j] = __builtin_amdgcn_mfma_f32_16x16x32_bf16(
                            af[0][(r4 - 1) * 3 + dx], bv, acc[1][0][j], 0, 0, 0);
                        acc[1][1][j] = __builtin_amdgcn_mfma_f32_16x16x32_bf16(
                            af[1][(r4 - 1) * 3 + dx], bv, acc[1][1][j], 0, 0, 0);
                    }
                }
            }
        }
        __syncthreads();  // next buffer staged AND this buffer's readers done
    }

    // epilogue: C/D layout col=lane&15 (px), row=quad*4+reg (co)
    const float ms = 1.0f / 48.0f;
#pragma unroll
    for (int wr = 0; wr < 2; ++wr) {
        int gy = Y0 + rp * 2 + wr;
#pragma unroll
        for (int m = 0; m < 2; ++m) {
            int cobase = co0 + wco * 32 + m * 16 + quad * 4;
            float d0 = demod[b * COUT + cobase + 0] * ms;
            float d1 = demod[b * COUT + cobase + 1] * ms;
            float d2 = demod[b * COUT + cobase + 2] * ms;
            float d3 = demod[b * COUT + cobase + 3] * ms;
#pragma unroll
            for (int j = 0; j < 4; ++j) {
                int gx = j * 16 + n;
                size_t o = ((size_t)(b * COUT + cobase) * HH + gy) * WW + gx;
                out[o]                       = acc[wr][m][j][0] * d0;
                out[o + (size_t)HH * WW]     = acc[wr][m][j][1] * d1;
                out[o + (size_t)2 * HH * WW] = acc[wr][m][j][2] * d2;
                out[o + (size_t)3 * HH * WW] = acc[wr][m][j][3] * d3;
            }
        }
    }
}

extern "C" void kernel_launch(void* const* d_in, const int* in_sizes, int n_in,
                              void* d_out, int out_size, void* d_ws, size_t ws_size,
                              hipStream_t stream) {
    const float* x       = (const float*)d_in[0];  // [16,256,64,64]
    const float* style   = (const float*)d_in[1];  // [16,512]
    const float* weight  = (const float*)d_in[2];  // [256,256,3,3]
    const float* style_w = (const float*)d_in[3];  // [512,256]
    const float* style_b = (const float*)d_in[4];  // [256]
    float* out = (float*)d_out;

    // ws: s[4096]f | wsq[65536]f | demod[4096]f | wT[589824]bf16  (~1.5 MB)
    float* s     = (float*)d_ws;
    float* wsq   = s + BB * CIN;
    float* demod = wsq + COUT * CIN;
    __hip_bfloat16* wT = (__hip_bfloat16*)(demod + BB * COUT);

    style_proj_kernel<<<BB, CIN, 0, stream>>>(style, style_w, style_b, s);
    wsq_kernel<<<(COUT * CIN) / 256, 256, 0, stream>>>(weight, wsq);
    demod_kernel<<<dim3(COUT / 4, BB), 256, 0, stream>>>(wsq, s, demod);
    wconv_kernel<<<COUT, CIN, 0, stream>>>(weight, wT);

    conv_mfma_kernel<<<dim3(HH / 4, COUT / 64, BB), 256, 0, stream>>>(
        x, wT, s, demod, out);
}